// Round 4
// baseline (483.486 us; speedup 1.0000x reference)
//
#include <hip/hip_runtime.h>

typedef unsigned short u16;
typedef unsigned int u32;
typedef float f32x4 __attribute__((ext_vector_type(4)));
typedef float f32x2 __attribute__((ext_vector_type(2)));
typedef short s16x8 __attribute__((ext_vector_type(8)));
typedef __bf16 bf16x8 __attribute__((ext_vector_type(8)));

#define NNODE 50000
#define NEDGE 200000
#define INV_SQRT3 0.57735026918962576f
#define INV_SQRT_FAN 0.0034938562148434216f  /* 1/sqrt(256^2+128^2) */

__device__ inline float b2f(u16 x) {
    unsigned u = ((unsigned)x) << 16;
    return __builtin_bit_cast(float, u);
}
__device__ inline u16 f2b(float f) {
    unsigned u = __builtin_bit_cast(unsigned, f);
    unsigned r = u + 0x7FFFu + ((u >> 16) & 1u);
    return (u16)(r >> 16);
}
__device__ inline float silu(float v) { return v / (1.f + __expf(-v)); }

__device__ inline float ld1(const void* p, long i, int m) {
    return m ? ((const float*)p)[i] : b2f(((const u16*)p)[i]);
}
__device__ inline void stout(void* o, long i, float v, int m) {
    if (m) ((float*)o)[i] = v; else ((u16*)o)[i] = f2b(v);
}

// ---------------- fp8 e4m3fn codec ----------------
#if defined(__has_builtin)
# if __has_builtin(__builtin_amdgcn_cvt_pk_f32_fp8) && __has_builtin(__builtin_amdgcn_cvt_pk_fp8_f32)
#  define HAVE_FP8 1
# endif
#endif
#ifndef HAVE_FP8
# define HAVE_FP8 0
#endif

__device__ inline int f2e4m3_soft(float f) {
    unsigned u = __builtin_bit_cast(unsigned, f);
    int s = (u >> 24) & 0x80;
    float a = __builtin_fabsf(f);
    if (a >= 464.f) return s | 0x7E;
    if (a < 0.015625f) {
        int q = (int)(a * 512.f + 0.5f);
        return s | q;
    }
    int e = (int)((u >> 23) & 0xFF) - 127;
    unsigned m = u & 0x7FFFFF;
    unsigned mq = (m + 0x80000) >> 20;
    if (mq == 8) { mq = 0; e += 1; }
    if (e > 8) return s | 0x7E;
    return s | ((e + 7) << 3) | (int)mq;
}
__device__ inline float e4m3f_soft(int b) {
    int em = b & 0x7F;
    float v;
    if (em >> 3) {
        unsigned bits = ((unsigned)((em >> 3) + 120) << 23) | ((unsigned)(em & 7) << 20);
        v = __builtin_bit_cast(float, bits);
    } else {
        v = (float)em * 0.001953125f;
    }
    return (b & 0x80) ? -v : v;
}
__device__ inline int enc2(float a, float b) {
#if HAVE_FP8
    return __builtin_amdgcn_cvt_pk_fp8_f32(a, b, 0, false) & 0xFFFF;
#else
    return f2e4m3_soft(a) | (f2e4m3_soft(b) << 8);
#endif
}
__device__ inline unsigned char enc1(float a) { return (unsigned char)(enc2(a, a) & 0xFF); }

__device__ inline float dot8(unsigned p, unsigned x, float acc) {
#if HAVE_FP8
    f32x2 p0 = __builtin_amdgcn_cvt_pk_f32_fp8((int)p, false);
    f32x2 p1 = __builtin_amdgcn_cvt_pk_f32_fp8((int)p, true);
    f32x2 x0 = __builtin_amdgcn_cvt_pk_f32_fp8((int)x, false);
    f32x2 x1 = __builtin_amdgcn_cvt_pk_f32_fp8((int)x, true);
    return acc + p0.x * x0.x + p0.y * x0.y + p1.x * x1.x + p1.y * x1.y;
#else
    float r = acc;
#pragma unroll
    for (int i = 0; i < 4; ++i)
        r += e4m3f_soft((p >> (8 * i)) & 0xFF) * e4m3f_soft((x >> (8 * i)) & 0xFF);
    return r;
#endif
}

// MFMA wrapper tolerant to either builtin signature.
template <typename V>
__device__ auto mfma_sel(V a, V b, f32x4 c, int)
    -> decltype(__builtin_amdgcn_mfma_f32_16x16x32_bf16(a, b, c, 0, 0, 0)) {
    return __builtin_amdgcn_mfma_f32_16x16x32_bf16(a, b, c, 0, 0, 0);
}
template <typename V>
__device__ f32x4 mfma_sel(V a, V b, f32x4 c, long) {
    bf16x8 aa = __builtin_bit_cast(bf16x8, a);
    bf16x8 bb = __builtin_bit_cast(bf16x8, b);
    return __builtin_amdgcn_mfma_f32_16x16x32_bf16(aa, bb, c, 0, 0, 0);
}
__device__ inline f32x4 mfma_bf16(s16x8 a, s16x8 b, f32x4 c) {
    return mfma_sel(a, b, c, 0);
}

// ---------------- async global -> LDS (16 B per lane, wave-uniform LDS base) ----
typedef __attribute__((address_space(1))) u32 AS1u32;
typedef __attribute__((address_space(3))) u32 AS3u32;
__device__ __forceinline__ void async16(const void* g, void* l) {
    __builtin_amdgcn_global_load_lds((AS1u32*)g, (AS3u32*)l, 16, 0, 0);
}

// ---------------- detect input storage dtype ----------------
__global__ __launch_bounds__(256) void detect_k(const void* __restrict__ h, int* __restrict__ flag) {
    int t = threadIdx.x;
    u16 w = ((const u16*)h)[2 * t];
    int tb = (w >> 8) & 0x7F;
    bool pl = (tb >= 0x38 && tb <= 0x41);
    unsigned long long b = __ballot(pl);
    __shared__ int cnt[4];
    if ((t & 63) == 0) cnt[t >> 6] = __popcll(b);
    __syncthreads();
    if (t == 0) {
        int s = cnt[0] + cnt[1] + cnt[2] + cnt[3];
        flag[0] = (s < 128) ? 1 : 0;  // 1 = f32 storage
    }
}

// ---------------- prep: transposes / packs / w_eff ----------------
__global__ __launch_bounds__(256) void prep_misc_k(
    const void* __restrict__ W00, const void* __restrict__ W11,
    const void* __restrict__ bW1, const void* __restrict__ Wv,
    const void* __restrict__ Wcoord, const void* __restrict__ aW2,
    const void* __restrict__ bW2, const void* __restrict__ bb1,
    u16* __restrict__ W00T, u16* __restrict__ W1p, u16* __restrict__ W2p,
    float* __restrict__ w1tp, float* __restrict__ w_eff,
    u16* __restrict__ W2ah, u16* __restrict__ W11T, float* __restrict__ b1f,
    const int* __restrict__ mflag)
{
    const int m = *mflag;
    int u = blockIdx.x * 256 + threadIdx.x;
    if (u < 65536) {                 // W00T[j][i] = W00[i][j]
        int j = u >> 8, i = u & 255;
        W00T[u] = f2b(ld1(W00, (long)i * 256 + j, m));
    } else if (u < 81920) {          // W1p: bond W1 fragment pack
        int v = u - 65536;
        int j = v & 7, ln = (v >> 3) & 63, tk = v >> 9;  // tk 0..31
        int tn = tk >> 1, kt = tk & 1;
        int hrow = tn * 16 + (ln & 15);
        int k = kt * 32 + (ln >> 4) * 8 + j;
        W1p[v] = f2b(ld1(bW1, (long)hrow * 65 + 1 + k, m));
    } else if (u < 86016) {          // W2p: bond W2 fragment pack (padded o>=5 -> 0)
        int v = u - 81920;
        int j = v & 7, ln = (v >> 3) & 63, kt = v >> 9;  // kt 0..7
        int o = ln & 15;
        int k = kt * 32 + (ln >> 4) * 8 + j;
        W2p[v] = (o < 5) ? f2b(ld1(bW2, (long)o * 256 + k, m)) : (u16)0;
    } else if (u < 86272) {          // w1tp
        int hd = u - 86016;
        w1tp[hd] = ld1(bW1, (long)hd * 65, m);
    } else if (u < 86400) {          // w_eff
        int c = u - 86272;
        float acc = 0.f;
        for (int d = 0; d < 128; ++d)
            acc += ld1(Wcoord, d, m) * ld1(Wv, (long)d * 128 + c, m);
        w_eff[c] = acc;
    } else if (u < 90496) {          // atom W2 (16x256)
        int v = u - 86400;
        W2ah[v] = f2b(ld1(aW2, v, m));
    } else if (u < 106880) {         // W11T[d][c] = W11[c][d]
        int v = u - 90496;
        int d = v >> 7, c = v & 127;
        W11T[v] = f2b(ld1(W11, (long)c * 128 + d, m));
    } else if (u < 107136) {         // b1f: bond b1 as f32 table
        int hd = u - 106880;
        b1f[hd] = ld1(bb1, hd, m);
    }
}

// W1s = atom_W1 @ Ws_w; b1p = atom_W1@Ws_b + atom_b1
__global__ __launch_bounds__(256) void prep_w1s_k(
    const void* __restrict__ aW1, const void* __restrict__ Wsw,
    const void* __restrict__ Wsb, const void* __restrict__ ab1,
    u16* __restrict__ W1sh, float* __restrict__ b1p,
    const int* __restrict__ mflag)
{
    const int m = *mflag;
    int hd = blockIdx.x, s = threadIdx.x;
    float acc = 0.f;
    for (int j = 0; j < 256; ++j)
        acc += ld1(aW1, (long)hd * 256 + j, m) * ld1(Wsw, (long)j * 256 + s, m);
    W1sh[hd * 256 + s] = f2b(acc);
    if (s == 0) {
        float b = ld1(ab1, hd, m);
        for (int j = 0; j < 256; ++j)
            b += ld1(aW1, (long)hd * 256 + j, m) * ld1(Wsb, j, m);
        b1p[hd] = b;
    }
}

// ---------------- zero the atom-head f32 partial buffer ----------------
__global__ __launch_bounds__(256) void zero_k(float4* __restrict__ p) {
    int t = blockIdx.x * 256 + threadIdx.x;
    if (t < 200000) p[t] = float4{0.f, 0.f, 0.f, 0.f};
}

// ---------------- shared pipelined 128x128 GEMM core (bf16 A via async16) -------
// C[128 x 128] += A[128 x K] * B^T, A u16 node-major, B row-major [outcol][K].
// LDS: S[0..16383] u16 = A dbuf (2 x 4 KB) | B dbuf (2 x 4 KB), linear [row][32].
// Schedule: stage(t+1) issued BEFORE compute(t); one __syncthreads per K-step.
__device__ __forceinline__ void gemm_core_128(
    const u16* __restrict__ Aptr, int lda,
    const u16* __restrict__ Bt, int ldb, int bcol0,
    long bm0, int K, u16* __restrict__ S, f32x4 acc[4][4])
{
    u16* As = S;            // [2][4096] u16
    u16* Bs = S + 8192;     // [2][4096] u16
    int tid = threadIdx.x;
    int lane = tid & 63, wave = tid >> 6;
    int sr = lane >> 2, sc = (lane & 3) * 8;   // lane -> (row-in-16, k-offset)

    auto stage = [&](int buf, int k0) {
#pragma unroll
        for (int i = 0; i < 2; ++i) {
            int row = wave * 32 + i * 16 + sr;
            async16(Bt + (long)(bcol0 + row) * ldb + k0 + sc,
                    Bs + buf * 4096 + wave * 1024 + i * 512);
            long grow = bm0 + row; if (grow >= NNODE) grow = NNODE - 1;
            async16(Aptr + grow * (long)lda + k0 + sc,
                    As + buf * 4096 + wave * 1024 + i * 512);
        }
    };

    int NT = K >> 5;
    stage(0, 0);
    __syncthreads();
    int wm = (wave & 1) * 64, wn = (wave >> 1) * 64;
    int lm = lane & 15, quad = lane >> 4;
    for (int t = 0; t < NT; ++t) {
        int cur = t & 1;
        if (t + 1 < NT) stage(cur ^ 1, (t + 1) * 32);
        const u16* Ac = As + cur * 4096;
        const u16* Bc = Bs + cur * 4096;
        s16x8 af[4], bfr[4];
#pragma unroll
        for (int q = 0; q < 4; ++q) {
            af[q]  = *(const s16x8*)(Ac + (wm + q * 16 + lm) * 32 + quad * 8);
            bfr[q] = *(const s16x8*)(Bc + (wn + q * 16 + lm) * 32 + quad * 8);
        }
#pragma unroll
        for (int i = 0; i < 4; ++i)
#pragma unroll
            for (int j = 0; j < 4; ++j)
                acc[i][j] = mfma_bf16(af[i], bfr[j], acc[i][j]);
        __syncthreads();
    }
}

// ---------------- atom MLP: fused l1+l2 (split-K over col-halves, f32 atomics) --
__global__ __launch_bounds__(256) void mlp1_k(
    const u16* __restrict__ Xs16, const u16* __restrict__ Bh,
    const float* __restrict__ b1p, const u16* __restrict__ W2ah,
    float* __restrict__ outP)
{
    __shared__ __align__(16) u16 S[17408];   // staging (16384) then hid tile [128][136]
    int bid = blockIdx.x;
    int x = bid & 7, s = bid >> 3;
    int rb = (s >> 1) * 8 + x, cb = s & 1;   // needs grid = 8*98 = 784 blocks
    if (rb >= 391) return;
    long bm0 = (long)rb * 128;
    int bn0 = cb * 128;
    f32x4 acc[4][4] = {};
    gemm_core_128(Xs16, 256, Bh, 256, bn0, bm0, 256, S, acc);

    int tid = threadIdx.x, lane = tid & 63, wave = tid >> 6;
    int wm = (wave & 1) * 64, wn = (wave >> 1) * 64;
    int lm = lane & 15, quad = lane >> 4;
    // silu+bias -> bf16 hid tile in LDS, stride 136
#pragma unroll
    for (int j = 0; j < 4; ++j) {
        int col = wn + j * 16 + lm;
        float bb = b1p[bn0 + col];
#pragma unroll
        for (int i = 0; i < 4; ++i)
#pragma unroll
            for (int rr = 0; rr < 4; ++rr)
                S[(wm + i * 16 + quad * 4 + rr) * 136 + col] = f2b(silu(acc[i][j][rr] + bb));
    }
    __syncthreads();
    // layer 2 partial: out[128 x 16] over this block's 128 hidden cols
    const u16* wp = W2ah + lm * 256 + bn0;
#pragma unroll
    for (int rg = 0; rg < 2; ++rg) {
        int r0 = wave * 32 + rg * 16;
        f32x4 a2 = {0.f, 0.f, 0.f, 0.f};
#pragma unroll
        for (int k0 = 0; k0 < 128; k0 += 32) {
            s16x8 a = *(const s16x8*)(S + (r0 + lm) * 136 + k0 + quad * 8);
            s16x8 b = *(const s16x8*)(wp + k0 + quad * 8);
            a2 = mfma_bf16(a, b, a2);
        }
#pragma unroll
        for (int rr = 0; rr < 4; ++rr) {
            long grow = bm0 + r0 + quad * 4 + rr;
            if (grow < NNODE)
                atomicAdd(outP + grow * 16 + lm, a2[rr]);
        }
    }
}

// ---------------- atom head finalize: bias + dtype store (4 elems/thread) -------
__global__ __launch_bounds__(256) void fin_atom_k(
    const float* __restrict__ outP, const void* __restrict__ b2v,
    void* __restrict__ out, const int* __restrict__ mflag)
{
    const int m = *mflag;
    int t4 = blockIdx.x * 256 + threadIdx.x;   // 200000 quads
    if (t4 >= 200000) return;
    float4 v = *(const float4*)(outP + (long)t4 * 4);
    int b0i = (t4 * 4) & 15;
    float r0 = v.x + ld1(b2v, b0i + 0, m);
    float r1 = v.y + ld1(b2v, b0i + 1, m);
    float r2 = v.z + ld1(b2v, b0i + 2, m);
    float r3 = v.w + ld1(b2v, b0i + 3, m);
    if (m) {
        *(float4*)((float*)out + (long)t4 * 4) = float4{r0, r1, r2, r3};
    } else {
        u16 pk[4] = {f2b(r0), f2b(r1), f2b(r2), f2b(r3)};
        *(ushort4*)((u16*)out + (long)t4 * 4) = *(const ushort4*)pk;
    }
}

// ---------------- merged pack: Xs16, X8 (planar vec), xvp, r0 — one pass over h -
__global__ __launch_bounds__(256) void packx8_k(
    const void* __restrict__ h, u16* __restrict__ xvp,
    const float* __restrict__ w_eff, unsigned char* __restrict__ X8,
    u16* __restrict__ Xs16, void* __restrict__ out,
    const int* __restrict__ mflag)
{
    const int m = *mflag;
    int lane = threadIdx.x & 63, w = threadIdx.x >> 6;
    int node = blockIdx.x * 4 + w;
    if (node >= NNODE) return;
    // scalar part: 4 elems/lane -> fp8 + bf16
    float s4[4];
    if (m) {
        float4 v = *(const float4*)((const float*)h + (long)node * 640 + lane * 4);
        s4[0] = v.x; s4[1] = v.y; s4[2] = v.z; s4[3] = v.w;
    } else {
        ushort4 v = *(const ushort4*)((const u16*)h + (long)node * 640 + lane * 4);
        s4[0] = b2f(v.x); s4[1] = b2f(v.y); s4[2] = b2f(v.z); s4[3] = b2f(v.w);
    }
    unsigned sp = (unsigned)enc2(s4[0], s4[1]) | ((unsigned)enc2(s4[2], s4[3]) << 16);
    *(unsigned*)(X8 + (long)node * 640 + lane * 4) = sp;
    u16 sx[4] = {f2b(s4[0]), f2b(s4[1]), f2b(s4[2]), f2b(s4[3])};
    *(ushort4*)(Xs16 + (long)node * 256 + lane * 4) = *(const ushort4*)sx;
    // vector part: 6 elems/lane (c=2*lane, 2*lane+1; z=0,1,2 interleaved)
    float a[6];
    if (m) {
        const float* p = (const float*)h + (long)node * 640 + 256 + lane * 6;
        float2 v0 = *(const float2*)p;
        float2 v1 = *(const float2*)(p + 2);
        float2 v2 = *(const float2*)(p + 4);
        a[0] = v0.x; a[1] = v0.y; a[2] = v1.x; a[3] = v1.y; a[4] = v2.x; a[5] = v2.y;
    } else {
        const u16* p = (const u16*)h + (long)node * 640 + 256 + lane * 6;
        ushort2 v0 = *(const ushort2*)p;
        ushort2 v1 = *(const ushort2*)(p + 2);
        ushort2 v2 = *(const ushort2*)(p + 4);
        a[0] = b2f(v0.x); a[1] = b2f(v0.y); a[2] = b2f(v1.x);
        a[3] = b2f(v1.y); a[4] = b2f(v2.x); a[5] = b2f(v2.y);
    }
#pragma unroll
    for (int z = 0; z < 3; ++z) {
        unsigned pk = (unsigned)f2b(a[z]) | ((unsigned)f2b(a[z + 3]) << 16);
        *(unsigned*)(xvp + (long)z * 6400000 + (long)node * 128 + lane * 2) = pk;
        *(unsigned short*)(X8 + (long)node * 640 + 256 + z * 128 + lane * 2) =
            (unsigned short)enc2(a[z], a[z + 3]);
    }
    // fused r0
    float2 we = *(const float2*)(w_eff + lane * 2);
    float s0 = a[0] * we.x + a[3] * we.y;
    float s1 = a[1] * we.x + a[4] * we.y;
    float s2 = a[2] * we.x + a[5] * we.y;
#pragma unroll
    for (int off = 32; off > 0; off >>= 1) {
        s0 += __shfl_down(s0, off);
        s1 += __shfl_down(s1, off);
        s2 += __shfl_down(s2, off);
    }
    if (lane == 0) {
        stout(out, 800000L + (long)node * 3 + 0, s0, m);
        stout(out, 800000L + (long)node * 3 + 1, s1, m);
        stout(out, 800000L + (long)node * 3 + 2, s2, m);
    }
}

// ---------------- combined PQ GEMM -> fp8 (planar Q), pipelined core ------------
// cb 0,1: P = Xs16@W00 (K=256) -> cols cb*128. cb 2,3,4: Q_z = xvp_z@W11 (K=128)
// -> planar cols 256 + z*128 (matches packx8_k's X8 layout).
__global__ __launch_bounds__(256) void gemm8n_k(
    const u16* __restrict__ Xs16, const u16* __restrict__ xvp,
    const u16* __restrict__ W00T, const u16* __restrict__ W11T,
    unsigned char* __restrict__ PQ8, float s00, float s11)
{
    __shared__ __align__(16) u16 S[16384];
    int bid = blockIdx.x;
    int x = bid & 7, s = bid >> 3;
    int rb = (s / 5) * 8 + x, cb = s % 5;    // grid = 8*245 = 1960 blocks
    if (rb >= 391) return;
    const bool qp = (cb >= 2);
    int z = cb - 2;
    long bm0 = (long)rb * 128;
    f32x4 acc[4][4] = {};
    if (qp)
        gemm_core_128(xvp + (long)z * 6400000, 128, W11T, 128, 0, bm0, 128, S, acc);
    else
        gemm_core_128(Xs16, 256, W00T, 256, cb * 128, bm0, 256, S, acc);

    float scale = qp ? s11 : s00;
    int colbase = qp ? (256 + z * 128) : cb * 128;
    unsigned char* C8 = (unsigned char*)S;
    int tid = threadIdx.x, lane = tid & 63, wave = tid >> 6;
    int wm = (wave & 1) * 64, wn = (wave >> 1) * 64;
    int lm = lane & 15, quad = lane >> 4;
#pragma unroll
    for (int j = 0; j < 4; ++j) {
        int col = wn + j * 16 + lm;
#pragma unroll
        for (int i = 0; i < 4; ++i)
#pragma unroll
            for (int rr = 0; rr < 4; ++rr) {
                int row = wm + i * 16 + quad * 4 + rr;
                C8[row * 128 + col] = enc1(scale * acc[i][j][rr]);
            }
    }
    __syncthreads();
#pragma unroll
    for (int v = 0; v < 4; ++v) {
        int idx = v * 256 + tid;
        int row = idx >> 3, seg = idx & 7;
        long grow = bm0 + row;
        if (grow < NNODE)
            *(uint4*)(PQ8 + grow * 640 + colbase + seg * 16) =
                *(const uint4*)(C8 + row * 128 + seg * 16);
    }
}

// ---------------- bond head: swapped-operand layer1 -> b64 LDS writes -----------
// Layer1 computes D = W1 x E^T (operand-swapped): lane holds edge=lm fixed,
// hidden = tn*16 + quad*4 + rr (4 CONSECUTIVE hidden cols) -> one ds_write_b64
// per tn instead of 4 scalar b16 writes. Layer2 unchanged.
__global__ __launch_bounds__(256) void bond_fused_k(
    const void* __restrict__ A, const u16* __restrict__ W1p,
    const float* __restrict__ b1f, const u16* __restrict__ W2p,
    const void* __restrict__ b2v, const float* __restrict__ tp,
    const float* __restrict__ w1tp, void* __restrict__ out, long obase,
    const int* __restrict__ mflag)
{
    const int m = *mflag;
    __shared__ __align__(16) u16 hidS[4][16][264];
    int tid = threadIdx.x, lane = tid & 63, w = tid >> 6;
    int lm = lane & 15, quad = lane >> 4;
    int e0 = (blockIdx.x * 4 + w) * 16;
    s16x8 af0, af1;
    long base = (long)(e0 + lm) * 64 + quad * 8;
    if (m) {
        const float* ap = (const float*)A + base;
        float4 a0 = *(const float4*)ap,        a1 = *(const float4*)(ap + 4);
        float4 a2 = *(const float4*)(ap + 32), a3 = *(const float4*)(ap + 36);
        u16 t0[8] = {f2b(a0.x), f2b(a0.y), f2b(a0.z), f2b(a0.w),
                     f2b(a1.x), f2b(a1.y), f2b(a1.z), f2b(a1.w)};
        u16 t1[8] = {f2b(a2.x), f2b(a2.y), f2b(a2.z), f2b(a2.w),
                     f2b(a3.x), f2b(a3.y), f2b(a3.z), f2b(a3.w)};
        af0 = *(const s16x8*)t0; af1 = *(const s16x8*)t1;
    } else {
        af0 = *(const s16x8*)((const u16*)A + base);
        af1 = *(const s16x8*)((const u16*)A + base + 32);
    }
    float tpe = tp[e0 + lm];
    // layer 1 (swapped): C row = hidden-in-tn (quad*4+rr), col = edge (lm)
    f32x4 acc1[16];
#pragma unroll
    for (int tn = 0; tn < 16; ++tn) {
        s16x8 b0 = *(const s16x8*)(W1p + ((tn * 2 + 0) * 64 + lane) * 8);
        s16x8 b1w = *(const s16x8*)(W1p + ((tn * 2 + 1) * 64 + lane) * 8);
        f32x4 a = {0.f, 0.f, 0.f, 0.f};
        a = mfma_bf16(b0, af0, a);
        a = mfma_bf16(b1w, af1, a);
        acc1[tn] = a;
    }
    // silu + bias + tp*w1t -> one ushort4 LDS write per tn
#pragma unroll
    for (int tn = 0; tn < 16; ++tn) {
        int hc0 = tn * 16 + quad * 4;
        float4 bb = *(const float4*)(b1f + hc0);
        float4 wt = *(const float4*)(w1tp + hc0);
        u16 pk[4];
        pk[0] = f2b(silu(acc1[tn][0] + bb.x + tpe * wt.x));
        pk[1] = f2b(silu(acc1[tn][1] + bb.y + tpe * wt.y));
        pk[2] = f2b(silu(acc1[tn][2] + bb.z + tpe * wt.z));
        pk[3] = f2b(silu(acc1[tn][3] + bb.w + tpe * wt.w));
        *(ushort4*)&hidS[w][lm][hc0] = *(const ushort4*)pk;
    }
    // layer 2: A = hid (m=edge=lm, k=h), B = W2p (n=o). C: row=edge, col=o.
    f32x4 acc2 = {0.f, 0.f, 0.f, 0.f};
#pragma unroll
    for (int kt = 0; kt < 8; ++kt) {
        s16x8 a = *(const s16x8*)&hidS[w][lm][kt * 32 + quad * 8];
        s16x8 b = *(const s16x8*)(W2p + (kt * 64 + lane) * 8);
        acc2 = mfma_bf16(a, b, acc2);
    }
    if (lm < 5) {
        float b2 = ld1(b2v, lm, m);
#pragma unroll
        for (int rr = 0; rr < 4; ++rr) {
            int e = e0 + quad * 4 + rr;
            stout(out, obase + (long)e * 5 + lm, acc2[rr] + b2, m);
        }
    }
}

// ---------------- tp: 16-lanes-per-edge fp8 640-dot ----------------
__global__ __launch_bounds__(256) void tp_k(
    const int* __restrict__ ei, const unsigned char* __restrict__ PQ8,
    const unsigned char* __restrict__ X8, float* __restrict__ tp)
{
    int tid = threadIdx.x;
    int sub = tid & 15;
    int e = blockIdx.x * 16 + (tid >> 4);
    if (e >= NEDGE) return;
    int row = ei[e], col = ei[NEDGE + e];
    const unsigned char* pq = PQ8 + (long)row * 640;
    const unsigned char* xp = X8 + (long)col * 640;
    uint4 p0 = *(const uint4*)(pq + sub * 16);
    uint4 x0 = *(const uint4*)(xp + sub * 16);
    uint4 p1 = *(const uint4*)(pq + 256 + sub * 16);
    uint4 x1 = *(const uint4*)(xp + 256 + sub * 16);
    uint2 p2 = *(const uint2*)(pq + 512 + sub * 8);
    uint2 x2 = *(const uint2*)(xp + 512 + sub * 8);
    float acc = 0.f;
    acc = dot8(p0.x, x0.x, acc); acc = dot8(p0.y, x0.y, acc);
    acc = dot8(p0.z, x0.z, acc); acc = dot8(p0.w, x0.w, acc);
    acc = dot8(p1.x, x1.x, acc); acc = dot8(p1.y, x1.y, acc);
    acc = dot8(p1.z, x1.z, acc); acc = dot8(p1.w, x1.w, acc);
    acc = dot8(p2.x, x2.x, acc); acc = dot8(p2.y, x2.y, acc);
#pragma unroll
    for (int off = 8; off > 0; off >>= 1) acc += __shfl_down(acc, off);
    if (sub == 0) tp[e] = acc * 0.0625f;
}

extern "C" void kernel_launch(void* const* d_in, const int* in_sizes, int n_in,
                              void* d_out, int out_size, void* d_ws, size_t ws_size,
                              hipStream_t stream) {
    (void)in_sizes; (void)n_in; (void)out_size; (void)ws_size;
    const void* h      = d_in[0];
    const void* e_fin  = d_in[1];
    const int*  ei     = (const int*)d_in[4];
    const void* Ws_w   = d_in[5];
    const void* Ws_b   = d_in[6];
    const void* Wv     = d_in[7];
    const void* Wcoord = d_in[8];
    const void* W00    = d_in[9];
    const void* W11    = d_in[10];
    const void* aW1    = d_in[11];
    const void* ab1    = d_in[12];
    const void* aW2    = d_in[13];
    const void* ab2    = d_in[14];
    const void* bW1    = d_in[15];
    const void* bb1    = d_in[16];
    const void* bW2    = d_in[17];
    const void* bb2    = d_in[18];

    char* ws = (char*)d_ws;
    int*   mflag = (int*)(ws + 0);
    float* w1tp  = (float*)(ws + 512);
    float* w_eff = (float*)(ws + 2048);
    float* b1p   = (float*)(ws + 3072);
    u16*   W00T  = (u16*)(ws + 4096);       // -> 135168
    u16*   W1p   = (u16*)(ws + 135168);     // -> 167936
    u16*   W2p   = (u16*)(ws + 167936);     // -> 176128
    u16*   W1sh  = (u16*)(ws + 176128);     // -> 307200
    u16*   W2ah  = (u16*)(ws + 307200);     // -> 315392
    u16*   W11T  = (u16*)(ws + 315392);     // -> 348160
    float* tp    = (float*)(ws + 348160);   // -> 1148160
    float* b1f   = (float*)(ws + 1148160);  // -> 1149184 (256 f32)
    char*  R     = ws + 1149184;
    unsigned char* PQ8  = (unsigned char*)R;                  // 32 MB
    unsigned char* X8   = (unsigned char*)(R + 33554432);     // 32 MB
    u16*           xvp  = (u16*)(R + 67108864);               // 38.4 MB
    u16*           Xs16 = (u16*)(R + 105906176);              // 25.6 MB
    float*         outP = (float*)(R + 132120576);            // 3.2 MB

    detect_k<<<1, 256, 0, stream>>>(h, mflag);
    prep_misc_k<<<419, 256, 0, stream>>>(W00, W11, bW1, Wv, Wcoord, aW2, bW2, bb1,
                                         W00T, W1p, W2p, w1tp, w_eff,
                                         W2ah, W11T, b1f, mflag);
    prep_w1s_k<<<256, 256, 0, stream>>>(aW1, Ws_w, Ws_b, ab1, W1sh, b1p, mflag);
    zero_k<<<782, 256, 0, stream>>>((float4*)outP);

    // ---- one pass over h: Xs16 + X8 (planar) + xvp + fused r0 ----
    packx8_k<<<12500, 256, 0, stream>>>(h, xvp, w_eff, X8, Xs16, d_out, mflag);

    // ---- atom head: fused l1+l2 with f32 split-K atomics (grid MUST be 784) ----
    mlp1_k<<<784, 256, 0, stream>>>(Xs16, W1sh, b1p, W2ah, outP);
    fin_atom_k<<<782, 256, 0, stream>>>(outP, ab2, d_out, mflag);

    // ---- PQ8 (planar Q), all-bf16 async path ----
    gemm8n_k<<<1960, 256, 0, stream>>>(Xs16, xvp, W00T, W11T, PQ8,
                                       16.f * INV_SQRT_FAN,
                                       16.f * INV_SQRT_FAN * INV_SQRT3);
    tp_k<<<12500, 256, 0, stream>>>(ei, PQ8, X8, tp);

    // ---- bond head (swapped-operand layer1) ----
    bond_fused_k<<<3125, 256, 0, stream>>>(e_fin, W1p, b1f, W2p, bb2,
                                           tp, w1tp, d_out, 950000L, mflag);
}

// Round 5
// 448.142 us; speedup vs baseline: 1.0789x; 1.0789x over previous
//
#include <hip/hip_runtime.h>

typedef unsigned short u16;
typedef unsigned int u32;
typedef float f32x4 __attribute__((ext_vector_type(4)));
typedef float f32x2 __attribute__((ext_vector_type(2)));
typedef short s16x8 __attribute__((ext_vector_type(8)));
typedef __bf16 bf16x8 __attribute__((ext_vector_type(8)));

#define NNODE 50000
#define NEDGE 200000
#define INV_SQRT3 0.57735026918962576f
#define INV_SQRT_FAN 0.0034938562148434216f  /* 1/sqrt(256^2+128^2) */

__device__ inline float b2f(u16 x) {
    unsigned u = ((unsigned)x) << 16;
    return __builtin_bit_cast(float, u);
}
__device__ inline u16 f2b(float f) {
    unsigned u = __builtin_bit_cast(unsigned, f);
    unsigned r = u + 0x7FFFu + ((u >> 16) & 1u);
    return (u16)(r >> 16);
}
__device__ inline float silu(float v) { return v / (1.f + __expf(-v)); }

__device__ inline float ld1(const void* p, long i, int m) {
    return m ? ((const float*)p)[i] : b2f(((const u16*)p)[i]);
}
__device__ inline void stout(void* o, long i, float v, int m) {
    if (m) ((float*)o)[i] = v; else ((u16*)o)[i] = f2b(v);
}

// ---------------- fp8 e4m3fn codec ----------------
#if defined(__has_builtin)
# if __has_builtin(__builtin_amdgcn_cvt_pk_f32_fp8) && __has_builtin(__builtin_amdgcn_cvt_pk_fp8_f32)
#  define HAVE_FP8 1
# endif
#endif
#ifndef HAVE_FP8
# define HAVE_FP8 0
#endif

__device__ inline int f2e4m3_soft(float f) {
    unsigned u = __builtin_bit_cast(unsigned, f);
    int s = (u >> 24) & 0x80;
    float a = __builtin_fabsf(f);
    if (a >= 464.f) return s | 0x7E;
    if (a < 0.015625f) {
        int q = (int)(a * 512.f + 0.5f);
        return s | q;
    }
    int e = (int)((u >> 23) & 0xFF) - 127;
    unsigned m = u & 0x7FFFFF;
    unsigned mq = (m + 0x80000) >> 20;
    if (mq == 8) { mq = 0; e += 1; }
    if (e > 8) return s | 0x7E;
    return s | ((e + 7) << 3) | (int)mq;
}
__device__ inline float e4m3f_soft(int b) {
    int em = b & 0x7F;
    float v;
    if (em >> 3) {
        unsigned bits = ((unsigned)((em >> 3) + 120) << 23) | ((unsigned)(em & 7) << 20);
        v = __builtin_bit_cast(float, bits);
    } else {
        v = (float)em * 0.001953125f;
    }
    return (b & 0x80) ? -v : v;
}
__device__ inline int enc2(float a, float b) {
#if HAVE_FP8
    return __builtin_amdgcn_cvt_pk_fp8_f32(a, b, 0, false) & 0xFFFF;
#else
    return f2e4m3_soft(a) | (f2e4m3_soft(b) << 8);
#endif
}
__device__ inline unsigned char enc1(float a) { return (unsigned char)(enc2(a, a) & 0xFF); }

__device__ inline float dot8(unsigned p, unsigned x, float acc) {
#if HAVE_FP8
    f32x2 p0 = __builtin_amdgcn_cvt_pk_f32_fp8((int)p, false);
    f32x2 p1 = __builtin_amdgcn_cvt_pk_f32_fp8((int)p, true);
    f32x2 x0 = __builtin_amdgcn_cvt_pk_f32_fp8((int)x, false);
    f32x2 x1 = __builtin_amdgcn_cvt_pk_f32_fp8((int)x, true);
    return acc + p0.x * x0.x + p0.y * x0.y + p1.x * x1.x + p1.y * x1.y;
#else
    float r = acc;
#pragma unroll
    for (int i = 0; i < 4; ++i)
        r += e4m3f_soft((p >> (8 * i)) & 0xFF) * e4m3f_soft((x >> (8 * i)) & 0xFF);
    return r;
#endif
}

// MFMA wrapper tolerant to either builtin signature.
template <typename V>
__device__ auto mfma_sel(V a, V b, f32x4 c, int)
    -> decltype(__builtin_amdgcn_mfma_f32_16x16x32_bf16(a, b, c, 0, 0, 0)) {
    return __builtin_amdgcn_mfma_f32_16x16x32_bf16(a, b, c, 0, 0, 0);
}
template <typename V>
__device__ f32x4 mfma_sel(V a, V b, f32x4 c, long) {
    bf16x8 aa = __builtin_bit_cast(bf16x8, a);
    bf16x8 bb = __builtin_bit_cast(bf16x8, b);
    return __builtin_amdgcn_mfma_f32_16x16x32_bf16(aa, bb, c, 0, 0, 0);
}
__device__ inline f32x4 mfma_bf16(s16x8 a, s16x8 b, f32x4 c) {
    return mfma_sel(a, b, c, 0);
}

// ---------------- async global -> LDS (16 B per lane, wave-uniform LDS base) ----
typedef __attribute__((address_space(1))) u32 AS1u32;
typedef __attribute__((address_space(3))) u32 AS3u32;
__device__ __forceinline__ void async16(const void* g, void* l) {
    __builtin_amdgcn_global_load_lds((AS1u32*)g, (AS3u32*)l, 16, 0, 0);
}

// ---------------- detect input storage dtype ----------------
__global__ __launch_bounds__(256) void detect_k(const void* __restrict__ h, int* __restrict__ flag) {
    int t = threadIdx.x;
    u16 w = ((const u16*)h)[2 * t];
    int tb = (w >> 8) & 0x7F;
    bool pl = (tb >= 0x38 && tb <= 0x41);
    unsigned long long b = __ballot(pl);
    __shared__ int cnt[4];
    if ((t & 63) == 0) cnt[t >> 6] = __popcll(b);
    __syncthreads();
    if (t == 0) {
        int s = cnt[0] + cnt[1] + cnt[2] + cnt[3];
        flag[0] = (s < 128) ? 1 : 0;  // 1 = f32 storage
    }
}

// ---------------- prep: transposes / packs / w_eff ----------------
__global__ __launch_bounds__(256) void prep_misc_k(
    const void* __restrict__ W00, const void* __restrict__ W11,
    const void* __restrict__ bW1, const void* __restrict__ Wv,
    const void* __restrict__ Wcoord, const void* __restrict__ aW2,
    const void* __restrict__ bW2, const void* __restrict__ bb1,
    u16* __restrict__ W00T, u16* __restrict__ W1p, u16* __restrict__ W2p,
    float* __restrict__ w1tp, float* __restrict__ w_eff,
    u16* __restrict__ W2ah, u16* __restrict__ W11T, float* __restrict__ b1f,
    const int* __restrict__ mflag)
{
    const int m = *mflag;
    int u = blockIdx.x * 256 + threadIdx.x;
    if (u < 65536) {                 // W00T[j][i] = W00[i][j]
        int j = u >> 8, i = u & 255;
        W00T[u] = f2b(ld1(W00, (long)i * 256 + j, m));
    } else if (u < 81920) {          // W1p: bond W1 fragment pack
        int v = u - 65536;
        int j = v & 7, ln = (v >> 3) & 63, tk = v >> 9;  // tk 0..31
        int tn = tk >> 1, kt = tk & 1;
        int hrow = tn * 16 + (ln & 15);
        int k = kt * 32 + (ln >> 4) * 8 + j;
        W1p[v] = f2b(ld1(bW1, (long)hrow * 65 + 1 + k, m));
    } else if (u < 86016) {          // W2p: bond W2 fragment pack (padded o>=5 -> 0)
        int v = u - 81920;
        int j = v & 7, ln = (v >> 3) & 63, kt = v >> 9;  // kt 0..7
        int o = ln & 15;
        int k = kt * 32 + (ln >> 4) * 8 + j;
        W2p[v] = (o < 5) ? f2b(ld1(bW2, (long)o * 256 + k, m)) : (u16)0;
    } else if (u < 86272) {          // w1tp
        int hd = u - 86016;
        w1tp[hd] = ld1(bW1, (long)hd * 65, m);
    } else if (u < 86400) {          // w_eff
        int c = u - 86272;
        float acc = 0.f;
        for (int d = 0; d < 128; ++d)
            acc += ld1(Wcoord, d, m) * ld1(Wv, (long)d * 128 + c, m);
        w_eff[c] = acc;
    } else if (u < 90496) {          // atom W2 (16x256)
        int v = u - 86400;
        W2ah[v] = f2b(ld1(aW2, v, m));
    } else if (u < 106880) {         // W11T[d][c] = W11[c][d]
        int v = u - 90496;
        int d = v >> 7, c = v & 127;
        W11T[v] = f2b(ld1(W11, (long)c * 128 + d, m));
    } else if (u < 107136) {         // b1f: bond b1 as f32 table
        int hd = u - 106880;
        b1f[hd] = ld1(bb1, hd, m);
    }
}

// W1s = atom_W1 @ Ws_w (4-way ILP); b1p via block-parallel reduce
__global__ __launch_bounds__(256) void prep_w1s_k(
    const void* __restrict__ aW1, const void* __restrict__ Wsw,
    const void* __restrict__ Wsb, const void* __restrict__ ab1,
    u16* __restrict__ W1sh, float* __restrict__ b1p,
    const int* __restrict__ mflag)
{
    const int m = *mflag;
    int hd = blockIdx.x, s = threadIdx.x;
    float a0 = 0.f, a1 = 0.f, a2 = 0.f, a3 = 0.f;
    for (int j = 0; j < 256; j += 4) {
        float w0 = ld1(aW1, (long)hd * 256 + j + 0, m);
        float w1 = ld1(aW1, (long)hd * 256 + j + 1, m);
        float w2 = ld1(aW1, (long)hd * 256 + j + 2, m);
        float w3 = ld1(aW1, (long)hd * 256 + j + 3, m);
        a0 += w0 * ld1(Wsw, (long)(j + 0) * 256 + s, m);
        a1 += w1 * ld1(Wsw, (long)(j + 1) * 256 + s, m);
        a2 += w2 * ld1(Wsw, (long)(j + 2) * 256 + s, m);
        a3 += w3 * ld1(Wsw, (long)(j + 3) * 256 + s, m);
    }
    W1sh[hd * 256 + s] = f2b((a0 + a1) + (a2 + a3));
    // b1p[hd] = ab1[hd] + sum_j aW1[hd][j]*Wsb[j]  (block-parallel reduce)
    float pb = ld1(aW1, (long)hd * 256 + s, m) * ld1(Wsb, s, m);
#pragma unroll
    for (int off = 32; off > 0; off >>= 1) pb += __shfl_down(pb, off);
    __shared__ float red[4];
    if ((s & 63) == 0) red[s >> 6] = pb;
    __syncthreads();
    if (s == 0)
        b1p[hd] = ld1(ab1, hd, m) + red[0] + red[1] + red[2] + red[3];
}

// ---------------- zero the atom-head f32 partial buffer ----------------
__global__ __launch_bounds__(256) void zero_k(float4* __restrict__ p) {
    int t = blockIdx.x * 256 + threadIdx.x;
    if (t < 200000) p[t] = float4{0.f, 0.f, 0.f, 0.f};
}

// ---------------- shared pipelined 128x128 GEMM core (bf16 A via async16) -------
__device__ __forceinline__ void gemm_core_128(
    const u16* __restrict__ Aptr, int lda,
    const u16* __restrict__ Bt, int ldb, int bcol0,
    long bm0, int K, u16* __restrict__ S, f32x4 acc[4][4])
{
    u16* As = S;            // [2][4096] u16
    u16* Bs = S + 8192;     // [2][4096] u16
    int tid = threadIdx.x;
    int lane = tid & 63, wave = tid >> 6;
    int sr = lane >> 2, sc = (lane & 3) * 8;   // lane -> (row-in-16, k-offset)

    auto stage = [&](int buf, int k0) {
#pragma unroll
        for (int i = 0; i < 2; ++i) {
            int row = wave * 32 + i * 16 + sr;
            async16(Bt + (long)(bcol0 + row) * ldb + k0 + sc,
                    Bs + buf * 4096 + wave * 1024 + i * 512);
            long grow = bm0 + row; if (grow >= NNODE) grow = NNODE - 1;
            async16(Aptr + grow * (long)lda + k0 + sc,
                    As + buf * 4096 + wave * 1024 + i * 512);
        }
    };

    int NT = K >> 5;
    stage(0, 0);
    __syncthreads();
    int wm = (wave & 1) * 64, wn = (wave >> 1) * 64;
    int lm = lane & 15, quad = lane >> 4;
    for (int t = 0; t < NT; ++t) {
        int cur = t & 1;
        if (t + 1 < NT) stage(cur ^ 1, (t + 1) * 32);
        const u16* Ac = As + cur * 4096;
        const u16* Bc = Bs + cur * 4096;
        s16x8 af[4], bfr[4];
#pragma unroll
        for (int q = 0; q < 4; ++q) {
            af[q]  = *(const s16x8*)(Ac + (wm + q * 16 + lm) * 32 + quad * 8);
            bfr[q] = *(const s16x8*)(Bc + (wn + q * 16 + lm) * 32 + quad * 8);
        }
#pragma unroll
        for (int i = 0; i < 4; ++i)
#pragma unroll
            for (int j = 0; j < 4; ++j)
                acc[i][j] = mfma_bf16(af[i], bfr[j], acc[i][j]);
        __syncthreads();
    }
}

// ---------------- combined GEMM: atom L1+L2 (cb 0-1), P->fp8 (cb 2-3),
//                  Q->fp8 (cb 4-6). A read straight from h when bf16. ----------
__global__ __launch_bounds__(256) void gemmC_k(
    const void* __restrict__ h, const u16* __restrict__ Xs16,
    const u16* __restrict__ xvp,
    const u16* __restrict__ W1sh, const float* __restrict__ b1p,
    const u16* __restrict__ W2ah, float* __restrict__ outP,
    const u16* __restrict__ W00T, const u16* __restrict__ W11T,
    unsigned char* __restrict__ PQ8, float s00, float s11,
    const int* __restrict__ mflag)
{
    __shared__ __align__(16) u16 S[17408];   // staging 16384; mlp hid tile [128][136]
    int bid = blockIdx.x;
    int x = bid & 7, s = bid >> 3;
    int rb = (s / 7) * 8 + x, cb = s % 7;    // grid = 8 * 49*7 = 2744
    if (rb >= 391) return;
    const int m = *mflag;
    const u16* Ascal = m ? Xs16 : (const u16*)h;
    const int ldas = m ? 256 : 640;
    long bm0 = (long)rb * 128;

    f32x4 acc[4][4] = {};
    int tid = threadIdx.x, lane = tid & 63, wave = tid >> 6;
    int wm = (wave & 1) * 64, wn = (wave >> 1) * 64;
    int lm = lane & 15, quad = lane >> 4;

    if (cb < 2) {
        // ---- atom MLP layer1 (half-N split) + layer2 partial ----
        int bn0 = cb * 128;
        gemm_core_128(Ascal, ldas, W1sh, 256, bn0, bm0, 256, S, acc);
#pragma unroll
        for (int j = 0; j < 4; ++j) {
            int col = wn + j * 16 + lm;
            float bb = b1p[bn0 + col];
#pragma unroll
            for (int i = 0; i < 4; ++i)
#pragma unroll
                for (int rr = 0; rr < 4; ++rr)
                    S[(wm + i * 16 + quad * 4 + rr) * 136 + col] =
                        f2b(silu(acc[i][j][rr] + bb));
        }
        __syncthreads();
        const u16* wp = W2ah + lm * 256 + bn0;
#pragma unroll
        for (int rg = 0; rg < 2; ++rg) {
            int r0 = wave * 32 + rg * 16;
            f32x4 a2 = {0.f, 0.f, 0.f, 0.f};
#pragma unroll
            for (int k0 = 0; k0 < 128; k0 += 32) {
                s16x8 a = *(const s16x8*)(S + (r0 + lm) * 136 + k0 + quad * 8);
                s16x8 b = *(const s16x8*)(wp + k0 + quad * 8);
                a2 = mfma_bf16(a, b, a2);
            }
#pragma unroll
            for (int rr = 0; rr < 4; ++rr) {
                long grow = bm0 + r0 + quad * 4 + rr;
                if (grow < NNODE)
                    atomicAdd(outP + grow * 16 + lm, a2[rr]);
            }
        }
        return;
    }

    // ---- P / Q -> fp8 ----
    const bool qp = (cb >= 4);
    int z = cb - 4;
    if (qp)
        gemm_core_128(xvp + (long)z * 6400000, 128, W11T, 128, 0, bm0, 128, S, acc);
    else
        gemm_core_128(Ascal, ldas, W00T, 256, (cb - 2) * 128, bm0, 256, S, acc);

    float scale = qp ? s11 : s00;
    int colbase = qp ? (256 + z * 128) : (cb - 2) * 128;
    unsigned char* C8 = (unsigned char*)S;
#pragma unroll
    for (int j = 0; j < 4; ++j) {
        int col = wn + j * 16 + lm;
#pragma unroll
        for (int i = 0; i < 4; ++i)
#pragma unroll
            for (int rr = 0; rr < 4; ++rr) {
                int row = wm + i * 16 + quad * 4 + rr;
                C8[row * 128 + col] = enc1(scale * acc[i][j][rr]);
            }
    }
    __syncthreads();
#pragma unroll
    for (int v = 0; v < 4; ++v) {
        int idx = v * 256 + tid;
        int row = idx >> 3, seg = idx & 7;
        long grow = bm0 + row;
        if (grow < NNODE)
            *(uint4*)(PQ8 + grow * 640 + colbase + seg * 16) =
                *(const uint4*)(C8 + row * 128 + seg * 16);
    }
}

// ---------------- atom head finalize: bias + dtype store (4 elems/thread) -------
__global__ __launch_bounds__(256) void fin_atom_k(
    const float* __restrict__ outP, const void* __restrict__ b2v,
    void* __restrict__ out, const int* __restrict__ mflag)
{
    const int m = *mflag;
    int t4 = blockIdx.x * 256 + threadIdx.x;   // 200000 quads
    if (t4 >= 200000) return;
    float4 v = *(const float4*)(outP + (long)t4 * 4);
    int b0i = (t4 * 4) & 15;
    float r0 = v.x + ld1(b2v, b0i + 0, m);
    float r1 = v.y + ld1(b2v, b0i + 1, m);
    float r2 = v.z + ld1(b2v, b0i + 2, m);
    float r3 = v.w + ld1(b2v, b0i + 3, m);
    if (m) {
        *(float4*)((float*)out + (long)t4 * 4) = float4{r0, r1, r2, r3};
    } else {
        u16 pk[4] = {f2b(r0), f2b(r1), f2b(r2), f2b(r3)};
        *(ushort4*)((u16*)out + (long)t4 * 4) = *(const ushort4*)pk;
    }
}

// ---------------- merged pack: X8 (planar vec), xvp, r0 (+Xs16 iff f32) --------
__global__ __launch_bounds__(256) void packx8_k(
    const void* __restrict__ h, u16* __restrict__ xvp,
    const float* __restrict__ w_eff, unsigned char* __restrict__ X8,
    u16* __restrict__ Xs16, void* __restrict__ out,
    const int* __restrict__ mflag)
{
    const int m = *mflag;
    int lane = threadIdx.x & 63, w = threadIdx.x >> 6;
    int node = blockIdx.x * 4 + w;
    if (node >= NNODE) return;
    // scalar part: 4 elems/lane -> fp8 (+ bf16 copy only for f32 storage)
    float s4[4];
    if (m) {
        float4 v = *(const float4*)((const float*)h + (long)node * 640 + lane * 4);
        s4[0] = v.x; s4[1] = v.y; s4[2] = v.z; s4[3] = v.w;
        u16 sx[4] = {f2b(s4[0]), f2b(s4[1]), f2b(s4[2]), f2b(s4[3])};
        *(ushort4*)(Xs16 + (long)node * 256 + lane * 4) = *(const ushort4*)sx;
    } else {
        ushort4 v = *(const ushort4*)((const u16*)h + (long)node * 640 + lane * 4);
        s4[0] = b2f(v.x); s4[1] = b2f(v.y); s4[2] = b2f(v.z); s4[3] = b2f(v.w);
    }
    unsigned sp = (unsigned)enc2(s4[0], s4[1]) | ((unsigned)enc2(s4[2], s4[3]) << 16);
    *(unsigned*)(X8 + (long)node * 640 + lane * 4) = sp;
    // vector part: 6 elems/lane (c=2*lane, 2*lane+1; z=0,1,2 interleaved)
    float a[6];
    if (m) {
        const float* p = (const float*)h + (long)node * 640 + 256 + lane * 6;
        float2 v0 = *(const float2*)p;
        float2 v1 = *(const float2*)(p + 2);
        float2 v2 = *(const float2*)(p + 4);
        a[0] = v0.x; a[1] = v0.y; a[2] = v1.x; a[3] = v1.y; a[4] = v2.x; a[5] = v2.y;
    } else {
        const u16* p = (const u16*)h + (long)node * 640 + 256 + lane * 6;
        ushort2 v0 = *(const ushort2*)p;
        ushort2 v1 = *(const ushort2*)(p + 2);
        ushort2 v2 = *(const ushort2*)(p + 4);
        a[0] = b2f(v0.x); a[1] = b2f(v0.y); a[2] = b2f(v1.x);
        a[3] = b2f(v1.y); a[4] = b2f(v2.x); a[5] = b2f(v2.y);
    }
#pragma unroll
    for (int z = 0; z < 3; ++z) {
        unsigned pk = (unsigned)f2b(a[z]) | ((unsigned)f2b(a[z + 3]) << 16);
        *(unsigned*)(xvp + (long)z * 6400000 + (long)node * 128 + lane * 2) = pk;
        *(unsigned short*)(X8 + (long)node * 640 + 256 + z * 128 + lane * 2) =
            (unsigned short)enc2(a[z], a[z + 3]);
    }
    // fused r0
    float2 we = *(const float2*)(w_eff + lane * 2);
    float s0 = a[0] * we.x + a[3] * we.y;
    float s1 = a[1] * we.x + a[4] * we.y;
    float s2 = a[2] * we.x + a[5] * we.y;
#pragma unroll
    for (int off = 32; off > 0; off >>= 1) {
        s0 += __shfl_down(s0, off);
        s1 += __shfl_down(s1, off);
        s2 += __shfl_down(s2, off);
    }
    if (lane == 0) {
        stout(out, 800000L + (long)node * 3 + 0, s0, m);
        stout(out, 800000L + (long)node * 3 + 1, s1, m);
        stout(out, 800000L + (long)node * 3 + 2, s2, m);
    }
}

// ---------------- bond head: swapped-operand layer1 -> b64 LDS writes -----------
__global__ __launch_bounds__(256) void bond_fused_k(
    const void* __restrict__ A, const u16* __restrict__ W1p,
    const float* __restrict__ b1f, const u16* __restrict__ W2p,
    const void* __restrict__ b2v, const float* __restrict__ tp,
    const float* __restrict__ w1tp, void* __restrict__ out, long obase,
    const int* __restrict__ mflag)
{
    const int m = *mflag;
    __shared__ __align__(16) u16 hidS[4][16][264];
    int tid = threadIdx.x, lane = tid & 63, w = tid >> 6;
    int lm = lane & 15, quad = lane >> 4;
    int e0 = (blockIdx.x * 4 + w) * 16;
    s16x8 af0, af1;
    long base = (long)(e0 + lm) * 64 + quad * 8;
    if (m) {
        const float* ap = (const float*)A + base;
        float4 a0 = *(const float4*)ap,        a1 = *(const float4*)(ap + 4);
        float4 a2 = *(const float4*)(ap + 32), a3 = *(const float4*)(ap + 36);
        u16 t0[8] = {f2b(a0.x), f2b(a0.y), f2b(a0.z), f2b(a0.w),
                     f2b(a1.x), f2b(a1.y), f2b(a1.z), f2b(a1.w)};
        u16 t1[8] = {f2b(a2.x), f2b(a2.y), f2b(a2.z), f2b(a2.w),
                     f2b(a3.x), f2b(a3.y), f2b(a3.z), f2b(a3.w)};
        af0 = *(const s16x8*)t0; af1 = *(const s16x8*)t1;
    } else {
        af0 = *(const s16x8*)((const u16*)A + base);
        af1 = *(const s16x8*)((const u16*)A + base + 32);
    }
    float tpe = tp[e0 + lm];
    f32x4 acc1[16];
#pragma unroll
    for (int tn = 0; tn < 16; ++tn) {
        s16x8 b0 = *(const s16x8*)(W1p + ((tn * 2 + 0) * 64 + lane) * 8);
        s16x8 b1w = *(const s16x8*)(W1p + ((tn * 2 + 1) * 64 + lane) * 8);
        f32x4 a = {0.f, 0.f, 0.f, 0.f};
        a = mfma_bf16(b0, af0, a);
        a = mfma_bf16(b1w, af1, a);
        acc1[tn] = a;
    }
#pragma unroll
    for (int tn = 0; tn < 16; ++tn) {
        int hc0 = tn * 16 + quad * 4;
        float4 bb = *(const float4*)(b1f + hc0);
        float4 wt = *(const float4*)(w1tp + hc0);
        u16 pk[4];
        pk[0] = f2b(silu(acc1[tn][0] + bb.x + tpe * wt.x));
        pk[1] = f2b(silu(acc1[tn][1] + bb.y + tpe * wt.y));
        pk[2] = f2b(silu(acc1[tn][2] + bb.z + tpe * wt.z));
        pk[3] = f2b(silu(acc1[tn][3] + bb.w + tpe * wt.w));
        *(ushort4*)&hidS[w][lm][hc0] = *(const ushort4*)pk;
    }
    f32x4 acc2 = {0.f, 0.f, 0.f, 0.f};
#pragma unroll
    for (int kt = 0; kt < 8; ++kt) {
        s16x8 a = *(const s16x8*)&hidS[w][lm][kt * 32 + quad * 8];
        s16x8 b = *(const s16x8*)(W2p + (kt * 64 + lane) * 8);
        acc2 = mfma_bf16(a, b, acc2);
    }
    if (lm < 5) {
        float b2 = ld1(b2v, lm, m);
#pragma unroll
        for (int rr = 0; rr < 4; ++rr) {
            int e = e0 + quad * 4 + rr;
            stout(out, obase + (long)e * 5 + lm, acc2[rr] + b2, m);
        }
    }
}

// ---------------- tp: 16-lanes-per-edge fp8 640-dot ----------------
__global__ __launch_bounds__(256) void tp_k(
    const int* __restrict__ ei, const unsigned char* __restrict__ PQ8,
    const unsigned char* __restrict__ X8, float* __restrict__ tp)
{
    int tid = threadIdx.x;
    int sub = tid & 15;
    int e = blockIdx.x * 16 + (tid >> 4);
    if (e >= NEDGE) return;
    int row = ei[e], col = ei[NEDGE + e];
    const unsigned char* pq = PQ8 + (long)row * 640;
    const unsigned char* xp = X8 + (long)col * 640;
    uint4 p0 = *(const uint4*)(pq + sub * 16);
    uint4 x0 = *(const uint4*)(xp + sub * 16);
    uint4 p1 = *(const uint4*)(pq + 256 + sub * 16);
    uint4 x1 = *(const uint4*)(xp + 256 + sub * 16);
    uint2 p2 = *(const uint2*)(pq + 512 + sub * 8);
    uint2 x2 = *(const uint2*)(xp + 512 + sub * 8);
    float acc = 0.f;
    acc = dot8(p0.x, x0.x, acc); acc = dot8(p0.y, x0.y, acc);
    acc = dot8(p0.z, x0.z, acc); acc = dot8(p0.w, x0.w, acc);
    acc = dot8(p1.x, x1.x, acc); acc = dot8(p1.y, x1.y, acc);
    acc = dot8(p1.z, x1.z, acc); acc = dot8(p1.w, x1.w, acc);
    acc = dot8(p2.x, x2.x, acc); acc = dot8(p2.y, x2.y, acc);
#pragma unroll
    for (int off = 8; off > 0; off >>= 1) acc += __shfl_down(acc, off);
    if (sub == 0) tp[e] = acc * 0.0625f;
}

extern "C" void kernel_launch(void* const* d_in, const int* in_sizes, int n_in,
                              void* d_out, int out_size, void* d_ws, size_t ws_size,
                              hipStream_t stream) {
    (void)in_sizes; (void)n_in; (void)out_size; (void)ws_size;
    const void* h      = d_in[0];
    const void* e_fin  = d_in[1];
    const int*  ei     = (const int*)d_in[4];
    const void* Ws_w   = d_in[5];
    const void* Ws_b   = d_in[6];
    const void* Wv     = d_in[7];
    const void* Wcoord = d_in[8];
    const void* W00    = d_in[9];
    const void* W11    = d_in[10];
    const void* aW1    = d_in[11];
    const void* ab1    = d_in[12];
    const void* aW2    = d_in[13];
    const void* ab2    = d_in[14];
    const void* bW1    = d_in[15];
    const void* bb1    = d_in[16];
    const void* bW2    = d_in[17];
    const void* bb2    = d_in[18];

    char* ws = (char*)d_ws;
    int*   mflag = (int*)(ws + 0);
    float* w1tp  = (float*)(ws + 512);
    float* w_eff = (float*)(ws + 2048);
    float* b1p   = (float*)(ws + 3072);
    u16*   W00T  = (u16*)(ws + 4096);       // -> 135168
    u16*   W1p   = (u16*)(ws + 135168);     // -> 167936
    u16*   W2p   = (u16*)(ws + 167936);     // -> 176128
    u16*   W1sh  = (u16*)(ws + 176128);     // -> 307200
    u16*   W2ah  = (u16*)(ws + 307200);     // -> 315392
    u16*   W11T  = (u16*)(ws + 315392);     // -> 348160
    float* tp    = (float*)(ws + 348160);   // -> 1148160
    float* b1f   = (float*)(ws + 1148160);  // -> 1149184 (256 f32)
    char*  R     = ws + 1149184;
    unsigned char* PQ8  = (unsigned char*)R;                  // 32 MB
    unsigned char* X8   = (unsigned char*)(R + 33554432);     // 32 MB
    u16*           xvp  = (u16*)(R + 67108864);               // 38.4 MB
    u16*           Xs16 = (u16*)(R + 105906176);              // 25.6 MB (m=1 only)
    float*         outP = (float*)(R + 132120576);            // 3.2 MB

    detect_k<<<1, 256, 0, stream>>>(h, mflag);
    prep_misc_k<<<419, 256, 0, stream>>>(W00, W11, bW1, Wv, Wcoord, aW2, bW2, bb1,
                                         W00T, W1p, W2p, w1tp, w_eff,
                                         W2ah, W11T, b1f, mflag);
    prep_w1s_k<<<256, 256, 0, stream>>>(aW1, Ws_w, Ws_b, ab1, W1sh, b1p, mflag);
    zero_k<<<782, 256, 0, stream>>>((float4*)outP);

    // ---- one pass over h: X8 (planar) + xvp + fused r0 (+Xs16 iff f32) ----
    packx8_k<<<12500, 256, 0, stream>>>(h, xvp, w_eff, X8, Xs16, d_out, mflag);

    // ---- combined GEMM: atom l1+l2 (atomics) + P + Q -> fp8 ----
    gemmC_k<<<2744, 256, 0, stream>>>(h, Xs16, xvp, W1sh, b1p, W2ah, outP,
                                      W00T, W11T, PQ8,
                                      16.f * INV_SQRT_FAN,
                                      16.f * INV_SQRT_FAN * INV_SQRT3, mflag);
    fin_atom_k<<<782, 256, 0, stream>>>(outP, ab2, d_out, mflag);

    tp_k<<<12500, 256, 0, stream>>>(ei, PQ8, X8, tp);

    // ---- bond head (swapped-operand layer1) ----
    bond_fused_k<<<3125, 256, 0, stream>>>(e_fin, W1p, b1f, W2p, bb2,
                                           tp, w1tp, d_out, 950000L, mflag);
}

// Round 6
// 419.310 us; speedup vs baseline: 1.1531x; 1.0688x over previous
//
#include <hip/hip_runtime.h>

typedef unsigned short u16;
typedef unsigned int u32;
typedef float f32x4 __attribute__((ext_vector_type(4)));
typedef float f32x2 __attribute__((ext_vector_type(2)));
typedef short s16x8 __attribute__((ext_vector_type(8)));
typedef __bf16 bf16x8 __attribute__((ext_vector_type(8)));

#define NNODE 50000
#define NEDGE 200000
#define INV_SQRT3 0.57735026918962576f
#define INV_SQRT_FAN 0.0034938562148434216f  /* 1/sqrt(256^2+128^2) */

__device__ inline float b2f(u16 x) {
    unsigned u = ((unsigned)x) << 16;
    return __builtin_bit_cast(float, u);
}
__device__ inline u16 f2b(float f) {
    unsigned u = __builtin_bit_cast(unsigned, f);
    unsigned r = u + 0x7FFFu + ((u >> 16) & 1u);
    return (u16)(r >> 16);
}
__device__ inline float silu(float v) { return v / (1.f + __expf(-v)); }

__device__ inline float ld1(const void* p, long i, int m) {
    return m ? ((const float*)p)[i] : b2f(((const u16*)p)[i]);
}
__device__ inline void stout(void* o, long i, float v, int m) {
    if (m) ((float*)o)[i] = v; else ((u16*)o)[i] = f2b(v);
}

// ---------------- fp8 e4m3fn codec ----------------
#if defined(__has_builtin)
# if __has_builtin(__builtin_amdgcn_cvt_pk_f32_fp8) && __has_builtin(__builtin_amdgcn_cvt_pk_fp8_f32)
#  define HAVE_FP8 1
# endif
#endif
#ifndef HAVE_FP8
# define HAVE_FP8 0
#endif

__device__ inline int f2e4m3_soft(float f) {
    unsigned u = __builtin_bit_cast(unsigned, f);
    int s = (u >> 24) & 0x80;
    float a = __builtin_fabsf(f);
    if (a >= 464.f) return s | 0x7E;
    if (a < 0.015625f) {
        int q = (int)(a * 512.f + 0.5f);
        return s | q;
    }
    int e = (int)((u >> 23) & 0xFF) - 127;
    unsigned m = u & 0x7FFFFF;
    unsigned mq = (m + 0x80000) >> 20;
    if (mq == 8) { mq = 0; e += 1; }
    if (e > 8) return s | 0x7E;
    return s | ((e + 7) << 3) | (int)mq;
}
__device__ inline float e4m3f_soft(int b) {
    int em = b & 0x7F;
    float v;
    if (em >> 3) {
        unsigned bits = ((unsigned)((em >> 3) + 120) << 23) | ((unsigned)(em & 7) << 20);
        v = __builtin_bit_cast(float, bits);
    } else {
        v = (float)em * 0.001953125f;
    }
    return (b & 0x80) ? -v : v;
}
__device__ inline int enc2(float a, float b) {
#if HAVE_FP8
    return __builtin_amdgcn_cvt_pk_fp8_f32(a, b, 0, false) & 0xFFFF;
#else
    return f2e4m3_soft(a) | (f2e4m3_soft(b) << 8);
#endif
}
__device__ inline unsigned char enc1(float a) { return (unsigned char)(enc2(a, a) & 0xFF); }

__device__ inline float dot8(unsigned p, unsigned x, float acc) {
#if HAVE_FP8
    f32x2 p0 = __builtin_amdgcn_cvt_pk_f32_fp8((int)p, false);
    f32x2 p1 = __builtin_amdgcn_cvt_pk_f32_fp8((int)p, true);
    f32x2 x0 = __builtin_amdgcn_cvt_pk_f32_fp8((int)x, false);
    f32x2 x1 = __builtin_amdgcn_cvt_pk_f32_fp8((int)x, true);
    return acc + p0.x * x0.x + p0.y * x0.y + p1.x * x1.x + p1.y * x1.y;
#else
    float r = acc;
#pragma unroll
    for (int i = 0; i < 4; ++i)
        r += e4m3f_soft((p >> (8 * i)) & 0xFF) * e4m3f_soft((x >> (8 * i)) & 0xFF);
    return r;
#endif
}

// pack two f32 -> one u32 of two bf16 (RNE; bit-identical to f2b pair)
__device__ __forceinline__ u32 pk_bf16(float lo, float hi) {
#if defined(__gfx950__) || defined(__gfx942__)
    u32 r;
    asm("v_cvt_pk_bf16_f32 %0, %1, %2" : "=v"(r) : "v"(lo), "v"(hi));
    return r;
#else
    return (u32)f2b(lo) | ((u32)f2b(hi) << 16);
#endif
}

// MFMA wrapper tolerant to either builtin signature.
template <typename V>
__device__ auto mfma_sel(V a, V b, f32x4 c, int)
    -> decltype(__builtin_amdgcn_mfma_f32_16x16x32_bf16(a, b, c, 0, 0, 0)) {
    return __builtin_amdgcn_mfma_f32_16x16x32_bf16(a, b, c, 0, 0, 0);
}
template <typename V>
__device__ f32x4 mfma_sel(V a, V b, f32x4 c, long) {
    bf16x8 aa = __builtin_bit_cast(bf16x8, a);
    bf16x8 bb = __builtin_bit_cast(bf16x8, b);
    return __builtin_amdgcn_mfma_f32_16x16x32_bf16(aa, bb, c, 0, 0, 0);
}
__device__ inline f32x4 mfma_bf16(s16x8 a, s16x8 b, f32x4 c) {
    return mfma_sel(a, b, c, 0);
}

// ---------------- async global -> LDS (16 B per lane, wave-uniform LDS base) ----
typedef __attribute__((address_space(1))) u32 AS1u32;
typedef __attribute__((address_space(3))) u32 AS3u32;
__device__ __forceinline__ void async16(const void* g, void* l) {
    __builtin_amdgcn_global_load_lds((AS1u32*)g, (AS3u32*)l, 16, 0, 0);
}

// ---------------- launch 1: detect dtype + w_eff (one block) ----------------
__global__ __launch_bounds__(256) void detect_weff_k(
    const void* __restrict__ h, const void* __restrict__ Wv,
    const void* __restrict__ Wcoord, int* __restrict__ flag,
    float* __restrict__ w_eff)
{
    __shared__ int cnt[4];
    __shared__ int mfs;
    int t = threadIdx.x;
    u16 wbits = ((const u16*)h)[2 * t];
    int tb = (wbits >> 8) & 0x7F;
    bool pl = (tb >= 0x38 && tb <= 0x41);
    unsigned long long b = __ballot(pl);
    if ((t & 63) == 0) cnt[t >> 6] = __popcll(b);
    __syncthreads();
    if (t == 0) {
        int s = cnt[0] + cnt[1] + cnt[2] + cnt[3];
        mfs = (s < 128) ? 1 : 0;  // 1 = f32 storage
        flag[0] = mfs;
    }
    __syncthreads();
    const int m = mfs;
    if (t < 128) {
        float acc = 0.f;
        for (int d = 0; d < 128; ++d)
            acc += ld1(Wcoord, d, m) * ld1(Wv, (long)d * 128 + t, m);
        w_eff[t] = acc;
    }
}

// ---------------- launch 2: fused prep (w1s | packx8 | misc | zero) ------------
__global__ __launch_bounds__(256) void prep_all_k(
    const void* __restrict__ h,
    const void* __restrict__ aW1, const void* __restrict__ Wsw,
    const void* __restrict__ Wsb, const void* __restrict__ ab1,
    const void* __restrict__ W00, const void* __restrict__ W11,
    const void* __restrict__ bW1, const void* __restrict__ aW2,
    const void* __restrict__ bW2, const void* __restrict__ bb1,
    u16* __restrict__ W00T, u16* __restrict__ W1p, u16* __restrict__ W2p,
    float* __restrict__ w1tp, u16* __restrict__ W2ah, u16* __restrict__ W11T,
    float* __restrict__ b1f, u16* __restrict__ W1sh, float* __restrict__ b1p,
    u16* __restrict__ xvp, const float* __restrict__ w_eff,
    unsigned char* __restrict__ X8, u16* __restrict__ Xs16,
    float4* __restrict__ outP4, void* __restrict__ out,
    const int* __restrict__ mflag)
{
    const int m = *mflag;
    int bid = blockIdx.x;
    int tid = threadIdx.x;

    if (bid < 256) {
        // ---- prep_w1s: W1s = atom_W1 @ Ws_w (4-way ILP); b1p block-reduce ----
        int hd = bid, s = tid;
        float a0 = 0.f, a1 = 0.f, a2 = 0.f, a3 = 0.f;
        for (int j = 0; j < 256; j += 4) {
            float w0 = ld1(aW1, (long)hd * 256 + j + 0, m);
            float w1 = ld1(aW1, (long)hd * 256 + j + 1, m);
            float w2 = ld1(aW1, (long)hd * 256 + j + 2, m);
            float w3 = ld1(aW1, (long)hd * 256 + j + 3, m);
            a0 += w0 * ld1(Wsw, (long)(j + 0) * 256 + s, m);
            a1 += w1 * ld1(Wsw, (long)(j + 1) * 256 + s, m);
            a2 += w2 * ld1(Wsw, (long)(j + 2) * 256 + s, m);
            a3 += w3 * ld1(Wsw, (long)(j + 3) * 256 + s, m);
        }
        W1sh[hd * 256 + s] = f2b((a0 + a1) + (a2 + a3));
        float pb = ld1(aW1, (long)hd * 256 + s, m) * ld1(Wsb, s, m);
#pragma unroll
        for (int off = 32; off > 0; off >>= 1) pb += __shfl_down(pb, off);
        __shared__ float red[4];
        if ((s & 63) == 0) red[s >> 6] = pb;
        __syncthreads();
        if (s == 0)
            b1p[hd] = ld1(ab1, hd, m) + red[0] + red[1] + red[2] + red[3];
        return;
    }
    bid -= 256;

    if (bid < 12500) {
        // ---- packx8: X8 (planar) + xvp + fused r0 (+Xs16 iff f32) ----
        int lane = tid & 63, w = tid >> 6;
        int node = bid * 4 + w;
        if (node >= NNODE) return;
        float s4[4];
        if (m) {
            float4 v = *(const float4*)((const float*)h + (long)node * 640 + lane * 4);
            s4[0] = v.x; s4[1] = v.y; s4[2] = v.z; s4[3] = v.w;
            u16 sx[4] = {f2b(s4[0]), f2b(s4[1]), f2b(s4[2]), f2b(s4[3])};
            *(ushort4*)(Xs16 + (long)node * 256 + lane * 4) = *(const ushort4*)sx;
        } else {
            ushort4 v = *(const ushort4*)((const u16*)h + (long)node * 640 + lane * 4);
            s4[0] = b2f(v.x); s4[1] = b2f(v.y); s4[2] = b2f(v.z); s4[3] = b2f(v.w);
        }
        unsigned sp = (unsigned)enc2(s4[0], s4[1]) | ((unsigned)enc2(s4[2], s4[3]) << 16);
        *(unsigned*)(X8 + (long)node * 640 + lane * 4) = sp;
        float a[6];
        if (m) {
            const float* p = (const float*)h + (long)node * 640 + 256 + lane * 6;
            float2 v0 = *(const float2*)p;
            float2 v1 = *(const float2*)(p + 2);
            float2 v2 = *(const float2*)(p + 4);
            a[0] = v0.x; a[1] = v0.y; a[2] = v1.x; a[3] = v1.y; a[4] = v2.x; a[5] = v2.y;
        } else {
            const u16* p = (const u16*)h + (long)node * 640 + 256 + lane * 6;
            ushort2 v0 = *(const ushort2*)p;
            ushort2 v1 = *(const ushort2*)(p + 2);
            ushort2 v2 = *(const ushort2*)(p + 4);
            a[0] = b2f(v0.x); a[1] = b2f(v0.y); a[2] = b2f(v1.x);
            a[3] = b2f(v1.y); a[4] = b2f(v2.x); a[5] = b2f(v2.y);
        }
#pragma unroll
        for (int z = 0; z < 3; ++z) {
            unsigned pk = pk_bf16(a[z], a[z + 3]);
            *(unsigned*)(xvp + (long)z * 6400000 + (long)node * 128 + lane * 2) = pk;
            *(unsigned short*)(X8 + (long)node * 640 + 256 + z * 128 + lane * 2) =
                (unsigned short)enc2(a[z], a[z + 3]);
        }
        float2 we = *(const float2*)(w_eff + lane * 2);
        float s0 = a[0] * we.x + a[3] * we.y;
        float s1 = a[1] * we.x + a[4] * we.y;
        float s2 = a[2] * we.x + a[5] * we.y;
#pragma unroll
        for (int off = 32; off > 0; off >>= 1) {
            s0 += __shfl_down(s0, off);
            s1 += __shfl_down(s1, off);
            s2 += __shfl_down(s2, off);
        }
        if (lane == 0) {
            stout(out, 800000L + (long)node * 3 + 0, s0, m);
            stout(out, 800000L + (long)node * 3 + 1, s1, m);
            stout(out, 800000L + (long)node * 3 + 2, s2, m);
        }
        return;
    }
    bid -= 12500;

    if (bid < 419) {
        // ---- prep_misc ----
        int u = bid * 256 + tid;
        if (u < 65536) {                 // W00T[j][i] = W00[i][j]
            int j = u >> 8, i = u & 255;
            W00T[u] = f2b(ld1(W00, (long)i * 256 + j, m));
        } else if (u < 81920) {          // W1p: bond W1 fragment pack
            int v = u - 65536;
            int j = v & 7, ln = (v >> 3) & 63, tk = v >> 9;
            int tn = tk >> 1, kt = tk & 1;
            int hrow = tn * 16 + (ln & 15);
            int k = kt * 32 + (ln >> 4) * 8 + j;
            W1p[v] = f2b(ld1(bW1, (long)hrow * 65 + 1 + k, m));
        } else if (u < 86016) {          // W2p (padded o>=5 -> 0)
            int v = u - 81920;
            int j = v & 7, ln = (v >> 3) & 63, kt = v >> 9;
            int o = ln & 15;
            int k = kt * 32 + (ln >> 4) * 8 + j;
            W2p[v] = (o < 5) ? f2b(ld1(bW2, (long)o * 256 + k, m)) : (u16)0;
        } else if (u < 86272) {          // w1tp
            int hd = u - 86016;
            w1tp[hd] = ld1(bW1, (long)hd * 65, m);
        } else if (u < 90368) {          // atom W2 (16x256)
            int v = u - 86272;
            W2ah[v] = f2b(ld1(aW2, v, m));
        } else if (u < 106752) {         // W11T[d][c] = W11[c][d]
            int v = u - 90368;
            int d = v >> 7, c = v & 127;
            W11T[v] = f2b(ld1(W11, (long)c * 128 + d, m));
        } else if (u < 107008) {         // b1f: bond b1 as f32 table
            int hd = u - 106752;
            b1f[hd] = ld1(bb1, hd, m);
        }
        return;
    }
    bid -= 419;

    // ---- zero outP (782 blocks) ----
    int t = bid * 256 + tid;
    if (t < 200000) outP4[t] = float4{0.f, 0.f, 0.f, 0.f};
}

// ---------------- shared pipelined 128x128 GEMM core (bf16 A via async16) -------
__device__ __forceinline__ void gemm_core_128(
    const u16* __restrict__ Aptr, int lda,
    const u16* __restrict__ Bt, int ldb, int bcol0,
    long bm0, int K, u16* __restrict__ S, f32x4 acc[4][4])
{
    u16* As = S;            // [2][4096] u16
    u16* Bs = S + 8192;     // [2][4096] u16
    int tid = threadIdx.x;
    int lane = tid & 63, wave = tid >> 6;
    int sr = lane >> 2, sc = (lane & 3) * 8;

    auto stage = [&](int buf, int k0) {
#pragma unroll
        for (int i = 0; i < 2; ++i) {
            int row = wave * 32 + i * 16 + sr;
            async16(Bt + (long)(bcol0 + row) * ldb + k0 + sc,
                    Bs + buf * 4096 + wave * 1024 + i * 512);
            long grow = bm0 + row; if (grow >= NNODE) grow = NNODE - 1;
            async16(Aptr + grow * (long)lda + k0 + sc,
                    As + buf * 4096 + wave * 1024 + i * 512);
        }
    };

    int NT = K >> 5;
    stage(0, 0);
    __syncthreads();
    int wm = (wave & 1) * 64, wn = (wave >> 1) * 64;
    int lm = lane & 15, quad = lane >> 4;
    for (int t = 0; t < NT; ++t) {
        int cur = t & 1;
        if (t + 1 < NT) stage(cur ^ 1, (t + 1) * 32);
        const u16* Ac = As + cur * 4096;
        const u16* Bc = Bs + cur * 4096;
        s16x8 af[4], bfr[4];
#pragma unroll
        for (int q = 0; q < 4; ++q) {
            af[q]  = *(const s16x8*)(Ac + (wm + q * 16 + lm) * 32 + quad * 8);
            bfr[q] = *(const s16x8*)(Bc + (wn + q * 16 + lm) * 32 + quad * 8);
        }
#pragma unroll
        for (int i = 0; i < 4; ++i)
#pragma unroll
            for (int j = 0; j < 4; ++j)
                acc[i][j] = mfma_bf16(af[i], bfr[j], acc[i][j]);
        __syncthreads();
    }
}

// ---------------- launch 3: combined GEMM (atom l1+l2 | P->fp8 | Q->fp8) --------
__global__ __launch_bounds__(256) void gemmC_k(
    const void* __restrict__ h, const u16* __restrict__ Xs16,
    const u16* __restrict__ xvp,
    const u16* __restrict__ W1sh, const float* __restrict__ b1p,
    const u16* __restrict__ W2ah, float* __restrict__ outP,
    const u16* __restrict__ W00T, const u16* __restrict__ W11T,
    unsigned char* __restrict__ PQ8, float s00, float s11,
    const int* __restrict__ mflag)
{
    __shared__ __align__(16) u16 S[17408];
    int bid = blockIdx.x;
    int x = bid & 7, s = bid >> 3;
    int rb = (s / 7) * 8 + x, cb = s % 7;    // grid = 8 * 49*7 = 2744
    if (rb >= 391) return;
    const int m = *mflag;
    const u16* Ascal = m ? Xs16 : (const u16*)h;
    const int ldas = m ? 256 : 640;
    long bm0 = (long)rb * 128;

    f32x4 acc[4][4] = {};
    int tid = threadIdx.x, lane = tid & 63, wave = tid >> 6;
    int wm = (wave & 1) * 64, wn = (wave >> 1) * 64;
    int lm = lane & 15, quad = lane >> 4;

    if (cb < 2) {
        int bn0 = cb * 128;
        gemm_core_128(Ascal, ldas, W1sh, 256, bn0, bm0, 256, S, acc);
#pragma unroll
        for (int j = 0; j < 4; ++j) {
            int col = wn + j * 16 + lm;
            float bb = b1p[bn0 + col];
#pragma unroll
            for (int i = 0; i < 4; ++i)
#pragma unroll
                for (int rr = 0; rr < 4; ++rr)
                    S[(wm + i * 16 + quad * 4 + rr) * 136 + col] =
                        f2b(silu(acc[i][j][rr] + bb));
        }
        __syncthreads();
        const u16* wp = W2ah + lm * 256 + bn0;
#pragma unroll
        for (int rg = 0; rg < 2; ++rg) {
            int r0 = wave * 32 + rg * 16;
            f32x4 a2 = {0.f, 0.f, 0.f, 0.f};
#pragma unroll
            for (int k0 = 0; k0 < 128; k0 += 32) {
                s16x8 a = *(const s16x8*)(S + (r0 + lm) * 136 + k0 + quad * 8);
                s16x8 b = *(const s16x8*)(wp + k0 + quad * 8);
                a2 = mfma_bf16(a, b, a2);
            }
#pragma unroll
            for (int rr = 0; rr < 4; ++rr) {
                long grow = bm0 + r0 + quad * 4 + rr;
                if (grow < NNODE)
                    atomicAdd(outP + grow * 16 + lm, a2[rr]);
            }
        }
        return;
    }

    const bool qp = (cb >= 4);
    int z = cb - 4;
    if (qp)
        gemm_core_128(xvp + (long)z * 6400000, 128, W11T, 128, 0, bm0, 128, S, acc);
    else
        gemm_core_128(Ascal, ldas, W00T, 256, (cb - 2) * 128, bm0, 256, S, acc);

    float scale = qp ? s11 : s00;
    int colbase = qp ? (256 + z * 128) : (cb - 2) * 128;
    unsigned char* C8 = (unsigned char*)S;
#pragma unroll
    for (int j = 0; j < 4; ++j) {
        int col = wn + j * 16 + lm;
#pragma unroll
        for (int i = 0; i < 4; ++i)
#pragma unroll
            for (int rr = 0; rr < 4; ++rr) {
                int row = wm + i * 16 + quad * 4 + rr;
                C8[row * 128 + col] = enc1(scale * acc[i][j][rr]);
            }
    }
    __syncthreads();
#pragma unroll
    for (int v = 0; v < 4; ++v) {
        int idx = v * 256 + tid;
        int row = idx >> 3, seg = idx & 7;
        long grow = bm0 + row;
        if (grow < NNODE)
            *(uint4*)(PQ8 + grow * 640 + colbase + seg * 16) =
                *(const uint4*)(C8 + row * 128 + seg * 16);
    }
}

// ---------------- launch 4: tp (16 lanes/edge) | fin_atom ----------------------
__global__ __launch_bounds__(256) void tpfin_k(
    const int* __restrict__ ei, const unsigned char* __restrict__ PQ8,
    const unsigned char* __restrict__ X8, float* __restrict__ tp,
    const float* __restrict__ outP, const void* __restrict__ b2v,
    void* __restrict__ out, const int* __restrict__ mflag)
{
    int bid = blockIdx.x;
    int tid = threadIdx.x;
    if (bid < 12500) {
        int sub = tid & 15;
        int e = bid * 16 + (tid >> 4);
        if (e >= NEDGE) return;
        int row = ei[e], col = ei[NEDGE + e];
        const unsigned char* pq = PQ8 + (long)row * 640;
        const unsigned char* xp = X8 + (long)col * 640;
        uint4 p0 = *(const uint4*)(pq + sub * 16);
        uint4 x0 = *(const uint4*)(xp + sub * 16);
        uint4 p1 = *(const uint4*)(pq + 256 + sub * 16);
        uint4 x1 = *(const uint4*)(xp + 256 + sub * 16);
        uint2 p2 = *(const uint2*)(pq + 512 + sub * 8);
        uint2 x2 = *(const uint2*)(xp + 512 + sub * 8);
        float acc = 0.f;
        acc = dot8(p0.x, x0.x, acc); acc = dot8(p0.y, x0.y, acc);
        acc = dot8(p0.z, x0.z, acc); acc = dot8(p0.w, x0.w, acc);
        acc = dot8(p1.x, x1.x, acc); acc = dot8(p1.y, x1.y, acc);
        acc = dot8(p1.z, x1.z, acc); acc = dot8(p1.w, x1.w, acc);
        acc = dot8(p2.x, x2.x, acc); acc = dot8(p2.y, x2.y, acc);
#pragma unroll
        for (int off = 8; off > 0; off >>= 1) acc += __shfl_down(acc, off);
        if (sub == 0) tp[e] = acc * 0.0625f;
        return;
    }
    bid -= 12500;
    const int m = *mflag;
    int t4 = bid * 256 + tid;   // 200000 quads
    if (t4 >= 200000) return;
    float4 v = *(const float4*)(outP + (long)t4 * 4);
    int b0i = (t4 * 4) & 15;
    float r0 = v.x + ld1(b2v, b0i + 0, m);
    float r1 = v.y + ld1(b2v, b0i + 1, m);
    float r2 = v.z + ld1(b2v, b0i + 2, m);
    float r3 = v.w + ld1(b2v, b0i + 3, m);
    if (m) {
        *(float4*)((float*)out + (long)t4 * 4) = float4{r0, r1, r2, r3};
    } else {
        u16 pk[4] = {f2b(r0), f2b(r1), f2b(r2), f2b(r3)};
        *(ushort4*)((u16*)out + (long)t4 * 4) = *(const ushort4*)pk;
    }
}

// ---------------- launch 5: bond head (2-wave blocks, cvt_pk pack) --------------
__global__ __launch_bounds__(128) void bond_fused_k(
    const void* __restrict__ A, const u16* __restrict__ W1p,
    const float* __restrict__ b1f, const u16* __restrict__ W2p,
    const void* __restrict__ b2v, const float* __restrict__ tp,
    const float* __restrict__ w1tp, void* __restrict__ out, long obase,
    const int* __restrict__ mflag)
{
    const int m = *mflag;
    __shared__ __align__(16) u16 hidS[2][16][264];   // 16.9 KB -> 9 blocks/CU
    int tid = threadIdx.x, lane = tid & 63, w = tid >> 6;   // w in {0,1}
    int lm = lane & 15, quad = lane >> 4;
    int e0 = (blockIdx.x * 2 + w) * 16;
    s16x8 af0, af1;
    long base = (long)(e0 + lm) * 64 + quad * 8;
    if (m) {
        const float* ap = (const float*)A + base;
        float4 a0 = *(const float4*)ap,        a1 = *(const float4*)(ap + 4);
        float4 a2 = *(const float4*)(ap + 32), a3 = *(const float4*)(ap + 36);
        u16 t0[8] = {f2b(a0.x), f2b(a0.y), f2b(a0.z), f2b(a0.w),
                     f2b(a1.x), f2b(a1.y), f2b(a1.z), f2b(a1.w)};
        u16 t1[8] = {f2b(a2.x), f2b(a2.y), f2b(a2.z), f2b(a2.w),
                     f2b(a3.x), f2b(a3.y), f2b(a3.z), f2b(a3.w)};
        af0 = *(const s16x8*)t0; af1 = *(const s16x8*)t1;
    } else {
        af0 = *(const s16x8*)((const u16*)A + base);
        af1 = *(const s16x8*)((const u16*)A + base + 32);
    }
    float tpe = tp[e0 + lm];
    // layer 1 (operand-swapped): lane holds edge=lm, hidden = tn*16+quad*4+rr
    f32x4 acc1[16];
#pragma unroll
    for (int tn = 0; tn < 16; ++tn) {
        s16x8 b0 = *(const s16x8*)(W1p + ((tn * 2 + 0) * 64 + lane) * 8);
        s16x8 b1w = *(const s16x8*)(W1p + ((tn * 2 + 1) * 64 + lane) * 8);
        f32x4 a = {0.f, 0.f, 0.f, 0.f};
        a = mfma_bf16(b0, af0, a);
        a = mfma_bf16(b1w, af1, a);
        acc1[tn] = a;
    }
    // silu + bias + tp*w1t -> packed uint2 LDS write per tn
#pragma unroll
    for (int tn = 0; tn < 16; ++tn) {
        int hc0 = tn * 16 + quad * 4;
        float4 bb = *(const float4*)(b1f + hc0);
        float4 wt = *(const float4*)(w1tp + hc0);
        float f0 = silu(acc1[tn][0] + bb.x + tpe * wt.x);
        float f1 = silu(acc1[tn][1] + bb.y + tpe * wt.y);
        float f2 = silu(acc1[tn][2] + bb.z + tpe * wt.z);
        float f3 = silu(acc1[tn][3] + bb.w + tpe * wt.w);
        uint2 pk2 = make_uint2(pk_bf16(f0, f1), pk_bf16(f2, f3));
        *(uint2*)((u16*)&hidS[w][lm][0] + hc0) = pk2;
    }
    // layer 2
    f32x4 acc2 = {0.f, 0.f, 0.f, 0.f};
#pragma unroll
    for (int kt = 0; kt < 8; ++kt) {
        s16x8 a = *(const s16x8*)&hidS[w][lm][kt * 32 + quad * 8];
        s16x8 b = *(const s16x8*)(W2p + (kt * 64 + lane) * 8);
        acc2 = mfma_bf16(a, b, acc2);
    }
    if (lm < 5) {
        float b2 = ld1(b2v, lm, m);
#pragma unroll
        for (int rr = 0; rr < 4; ++rr) {
            int e = e0 + quad * 4 + rr;
            stout(out, obase + (long)e * 5 + lm, acc2[rr] + b2, m);
        }
    }
}

extern "C" void kernel_launch(void* const* d_in, const int* in_sizes, int n_in,
                              void* d_out, int out_size, void* d_ws, size_t ws_size,
                              hipStream_t stream) {
    (void)in_sizes; (void)n_in; (void)out_size; (void)ws_size;
    const void* h      = d_in[0];
    const void* e_fin  = d_in[1];
    const int*  ei     = (const int*)d_in[4];
    const void* Ws_w   = d_in[5];
    const void* Ws_b   = d_in[6];
    const void* Wv     = d_in[7];
    const void* Wcoord = d_in[8];
    const void* W00    = d_in[9];
    const void* W11    = d_in[10];
    const void* aW1    = d_in[11];
    const void* ab1    = d_in[12];
    const void* aW2    = d_in[13];
    const void* ab2    = d_in[14];
    const void* bW1    = d_in[15];
    const void* bb1    = d_in[16];
    const void* bW2    = d_in[17];
    const void* bb2    = d_in[18];

    char* ws = (char*)d_ws;
    int*   mflag = (int*)(ws + 0);
    float* w1tp  = (float*)(ws + 512);
    float* w_eff = (float*)(ws + 2048);
    float* b1p   = (float*)(ws + 3072);
    u16*   W00T  = (u16*)(ws + 4096);       // -> 135168
    u16*   W1p   = (u16*)(ws + 135168);     // -> 167936
    u16*   W2p   = (u16*)(ws + 167936);     // -> 176128
    u16*   W1sh  = (u16*)(ws + 176128);     // -> 307200
    u16*   W2ah  = (u16*)(ws + 307200);     // -> 315392
    u16*   W11T  = (u16*)(ws + 315392);     // -> 348160
    float* tp    = (float*)(ws + 348160);   // -> 1148160
    float* b1f   = (float*)(ws + 1148160);  // -> 1149184 (256 f32)
    char*  R     = ws + 1149184;
    unsigned char* PQ8  = (unsigned char*)R;                  // 32 MB
    unsigned char* X8   = (unsigned char*)(R + 33554432);     // 32 MB
    u16*           xvp  = (u16*)(R + 67108864);               // 38.4 MB
    u16*           Xs16 = (u16*)(R + 105906176);              // 25.6 MB (m=1 only)
    float*         outP = (float*)(R + 132120576);            // 3.2 MB

    // L1: dtype flag + w_eff (one block)
    detect_weff_k<<<1, 256, 0, stream>>>(h, Wv, Wcoord, mflag, w_eff);

    // L2: all prep in one launch: w1s(256) | packx8(12500) | misc(419) | zero(782)
    prep_all_k<<<13957, 256, 0, stream>>>(h, aW1, Ws_w, Ws_b, ab1,
                                          W00, W11, bW1, aW2, bW2, bb1,
                                          W00T, W1p, W2p, w1tp, W2ah, W11T, b1f,
                                          W1sh, b1p, xvp, w_eff, X8, Xs16,
                                          (float4*)outP, d_out, mflag);

    // L3: combined GEMM (atom l1+l2 atomics | P | Q -> fp8)
    gemmC_k<<<2744, 256, 0, stream>>>(h, Xs16, xvp, W1sh, b1p, W2ah, outP,
                                      W00T, W11T, PQ8,
                                      16.f * INV_SQRT_FAN,
                                      16.f * INV_SQRT_FAN * INV_SQRT3, mflag);

    // L4: tp(12500) | fin_atom(782)
    tpfin_k<<<13282, 256, 0, stream>>>(ei, PQ8, X8, tp, outP, ab2, d_out, mflag);

    // L5: bond head (2-wave blocks)
    bond_fused_k<<<6250, 128, 0, stream>>>(e_fin, W1p, b1f, W2p, bb2,
                                           tp, w1tp, d_out, 950000L, mflag);
}